// Round 1
// 871.959 us; speedup vs baseline: 1.0749x; 1.0749x over previous
//
#include <hip/hip_runtime.h>
#include <stdint.h>

#define NN 2048
#define FF 64
#define NB 32

typedef __attribute__((ext_vector_type(8))) short bf16x8;
typedef __attribute__((ext_vector_type(4))) float f32x4;

__device__ __forceinline__ uint16_t f2bf(float f) {
  uint32_t u = __builtin_bit_cast(uint32_t, f);
  return (uint16_t)((u + 0x7FFFu + ((u >> 16) & 1u)) >> 16);  // RNE truncation
}
__device__ __forceinline__ float bf2f(uint16_t h) {
  uint32_t u = ((uint32_t)h) << 16;
  return __builtin_bit_cast(float, u);
}

// ---------------- W [64(k)][64(f)] fp32 -> Wt [64(f)][64(k)] bf16 ----------------
__global__ void k_prep(const float* __restrict__ W, uint16_t* __restrict__ Wt) {
  int t = threadIdx.x;  // 256
  for (int i = 0; i < 16; ++i) {
    int idx = t * 16 + i;  // = k*64 + f
    int k = idx >> 6, f = idx & 63;
    Wt[f * 64 + k] = f2bf(W[idx]);
  }
}

// ---------------- xw = x @ W  (bf16 out), MFMA, Wt read direct from global/L2 ----
__global__ __launch_bounds__(256) void k_xw(const float* __restrict__ x,
                                            const uint16_t* __restrict__ Wt,
                                            uint16_t* __restrict__ xw) {
  __shared__ short As[64 * 72];  // x tile, bf16, padded stride 72
  int bid = blockIdx.x;
  int b = bid >> 5;
  int n0 = (bid & 31) * 64;
  int t = threadIdx.x;
  const float* xb = x + ((size_t)b * NN + n0) * FF;
  for (int i = 0; i < 4; ++i) {
    int idx = t + i * 256;  // 1024 float4 chunks
    int r = idx >> 4, c = (idx & 15) * 4;
    float4 v = *(const float4*)(xb + r * FF + c);
    uint32_t p0 = f2bf(v.x) | ((uint32_t)f2bf(v.y) << 16);
    uint32_t p1 = f2bf(v.z) | ((uint32_t)f2bf(v.w) << 16);
    uint2 pv = {p0, p1};
    *(uint2*)&As[r * 72 + c] = pv;
  }
  __syncthreads();
  int lane = t & 63, wave = t >> 6;
  int l16 = lane & 15, quad = lane >> 4;
  f32x4 acc[4] = {};
  for (int ks = 0; ks < 2; ++ks) {
    bf16x8 a = *(const bf16x8*)&As[(wave * 16 + l16) * 72 + ks * 32 + quad * 8];
    for (int fi = 0; fi < 4; ++fi) {
      bf16x8 bq = *(const bf16x8*)(Wt + (fi * 16 + l16) * 64 + ks * 32 + quad * 8);
      acc[fi] = __builtin_amdgcn_mfma_f32_16x16x32_bf16(a, bq, acc[fi], 0, 0, 0);
    }
  }
  for (int fi = 0; fi < 4; ++fi)
    for (int r = 0; r < 4; ++r) {
      int n = n0 + wave * 16 + quad * 4 + r;
      int f = fi * 16 + l16;
      xw[((size_t)b * NN + n) * FF + f] = f2bf(acc[fi][r]);
    }
}

// ---------------- transpose bf16 [B][2048][64] -> [B][64][2048] ------------------
__global__ __launch_bounds__(256) void k_tr(const uint16_t* __restrict__ src,
                                            uint16_t* __restrict__ dst) {
  __shared__ uint16_t T[64 * 72];
  int bid = blockIdx.x;
  int b = bid >> 5;
  int n0 = (bid & 31) * 64;
  int t = threadIdx.x;
  for (int j = 0; j < 2; ++j) {
    int n = (t >> 3) + j * 32;
    int f8 = (t & 7) * 8;
    uint4 v = *(const uint4*)(src + ((size_t)b * NN + n0 + n) * FF + f8);
    *(uint4*)&T[n * 72 + f8] = v;
  }
  __syncthreads();
  for (int j = 0; j < 2; ++j) {
    int f = (t >> 3) + j * 32;
    int n8 = (t & 7) * 8;
    uint4 v;
    uint16_t* tp = (uint16_t*)&v;
    for (int i = 0; i < 8; ++i) tp[i] = T[(n8 + i) * 72 + f];
    *(uint4*)(dst + ((size_t)b * FF + f) * NN + n0 + n8) = v;
  }
}

// ---------------- Y = A @ X  (A fp32 [2048][2048], X via Bt bf16 [64][2048]) -----
// EPI=0: write Y as bf16 to Yb.  EPI=1: out = ka*xw + kb*y1 + kc*Y + bias (fp32)
// K-loop is ROTATED per block (koff) so in-flight reads across the GPU cover all
// 32 distinct 256B column slabs of the 8KB-stride rows -> no HBM channel camping.
template <int EPI>
__global__ __launch_bounds__(256) void k_gemm(const float* __restrict__ adj,
                                              const uint16_t* __restrict__ Bt,
                                              uint16_t* __restrict__ Yb,
                                              const uint16_t* __restrict__ xw,
                                              const uint16_t* __restrict__ y1,
                                              const float* __restrict__ Kc,
                                              const float* __restrict__ bias,
                                              float* __restrict__ out) {
  __shared__ short As[128 * 72];  // 18 KiB, pad stride 72 bf16 (144 B)
  __shared__ short Bs[64 * 72];   //  9 KiB
  int bid = blockIdx.x;
  int b = bid & 31;               // batch-minor: batch b pinned to XCD b%8 for L2 reuse of Bt
  int rt = bid >> 5;
  int row0 = rt * 128;
  int koff = (((b * 11) + rt * 7) & 31) << 6;  // 64-aligned K rotation, spreads channel bits
  int t = threadIdx.x;
  const float* Ab = adj + (size_t)b * NN * NN + (size_t)row0 * NN;
  const uint16_t* Btb = Bt + (size_t)b * FF * NN;

  int ar = t >> 4, ac4 = (t & 15) * 4;   // A staging: 8 rows/thread, 16B each
  int bfb = t >> 3, bc8 = (t & 7) * 8;   // B staging: 2 rows/thread, 16B each

  float4 areg[8];
  uint4 breg[2];
  for (int i = 0; i < 8; ++i)
    areg[i] = *(const float4*)(Ab + (size_t)(ar + i * 16) * NN + koff + ac4);
  for (int j = 0; j < 2; ++j)
    breg[j] = *(const uint4*)(Btb + (size_t)(bfb + j * 32) * NN + koff + bc8);

  f32x4 acc[2][4] = {};
  int lane = t & 63, wave = t >> 6;
  int l16 = lane & 15, quad = lane >> 4;

  for (int it = 0; it < 32; ++it) {
    __syncthreads();  // prior iter's frag reads complete
    for (int i = 0; i < 8; ++i) {
      float4 v = areg[i];
      uint32_t p0 = f2bf(v.x) | ((uint32_t)f2bf(v.y) << 16);
      uint32_t p1 = f2bf(v.z) | ((uint32_t)f2bf(v.w) << 16);
      uint2 pv = {p0, p1};
      *(uint2*)&As[(ar + i * 16) * 72 + ac4] = pv;
    }
    for (int j = 0; j < 2; ++j)
      *(uint4*)&Bs[(bfb + j * 32) * 72 + bc8] = breg[j];
    __syncthreads();
    if (it + 1 < 32) {  // register prefetch of next (rotated) K-tile
      int kn = ((it + 1) * 64 + koff) & (NN - 1);
      for (int i = 0; i < 8; ++i)
        areg[i] = *(const float4*)(Ab + (size_t)(ar + i * 16) * NN + kn + ac4);
      for (int j = 0; j < 2; ++j)
        breg[j] = *(const uint4*)(Btb + (size_t)(bfb + j * 32) * NN + kn + bc8);
    }
    for (int ks = 0; ks < 2; ++ks) {
      bf16x8 af[2];
      for (int mi = 0; mi < 2; ++mi)
        af[mi] = *(const bf16x8*)&As[(wave * 32 + mi * 16 + l16) * 72 + ks * 32 + quad * 8];
      for (int fi = 0; fi < 4; ++fi) {
        bf16x8 bq = *(const bf16x8*)&Bs[(fi * 16 + l16) * 72 + ks * 32 + quad * 8];
        acc[0][fi] = __builtin_amdgcn_mfma_f32_16x16x32_bf16(af[0], bq, acc[0][fi], 0, 0, 0);
        acc[1][fi] = __builtin_amdgcn_mfma_f32_16x16x32_bf16(af[1], bq, acc[1][fi], 0, 0, 0);
      }
    }
  }

  if (EPI == 0) {
    for (int mi = 0; mi < 2; ++mi)
      for (int fi = 0; fi < 4; ++fi)
        for (int r = 0; r < 4; ++r) {
          int n = row0 + wave * 32 + mi * 16 + quad * 4 + r;
          int f = fi * 16 + l16;
          Yb[((size_t)b * NN + n) * FF + f] = f2bf(acc[mi][fi][r]);
        }
  } else {
    float ka = Kc[0] - Kc[2], kb = Kc[1], kc = 2.0f * Kc[2];
    for (int mi = 0; mi < 2; ++mi)
      for (int fi = 0; fi < 4; ++fi) {
        int f = fi * 16 + l16;
        float bv = bias[f];
        for (int r = 0; r < 4; ++r) {
          int n = row0 + wave * 32 + mi * 16 + quad * 4 + r;
          size_t idx = ((size_t)b * NN + n) * FF + f;
          out[idx] = ka * bf2f(xw[idx]) + kb * bf2f(y1[idx]) + kc * acc[mi][fi][r] + bv;
        }
      }
  }
}

extern "C" void kernel_launch(void* const* d_in, const int* in_sizes, int n_in,
                              void* d_out, int out_size, void* d_ws, size_t ws_size,
                              hipStream_t stream) {
  const float* x    = (const float*)d_in[0];
  const float* adj  = (const float*)d_in[1];
  const float* W    = (const float*)d_in[2];
  const float* K    = (const float*)d_in[3];
  const float* bias = (const float*)d_in[4];
  float* out = (float*)d_out;

  uint8_t* ws = (uint8_t*)d_ws;
  const size_t SZ = (size_t)NB * NN * FF * sizeof(uint16_t);  // 8 MiB per buffer
  uint16_t* xw_n = (uint16_t*)(ws);
  uint16_t* xwT  = (uint16_t*)(ws + SZ);
  uint16_t* y1_n = (uint16_t*)(ws + 2 * SZ);
  uint16_t* y1T  = (uint16_t*)(ws + 3 * SZ);
  uint16_t* Wt   = (uint16_t*)(ws + 4 * SZ);

  k_prep<<<dim3(1), dim3(256), 0, stream>>>(W, Wt);
  k_xw<<<dim3(1024), dim3(256), 0, stream>>>(x, Wt, xw_n);
  k_tr<<<dim3(1024), dim3(256), 0, stream>>>(xw_n, xwT);
  k_gemm<0><<<dim3(512), dim3(256), 0, stream>>>(adj, xwT, y1_n, nullptr, nullptr,
                                                 nullptr, nullptr, nullptr);
  k_tr<<<dim3(1024), dim3(256), 0, stream>>>(y1_n, y1T);
  k_gemm<1><<<dim3(512), dim3(256), 0, stream>>>(adj, y1T, nullptr, xw_n, y1_n,
                                                 K, bias, out);
}